// Round 2
// baseline (312.833 us; speedup 1.0000x reference)
//
#include <hip/hip_runtime.h>

#define EPSF 1e-5f
#define FINF __builtin_huge_valf()

// Wave-local LDS fence: drain our own ds ops; "memory" clobber stops the
// compiler from reordering LDS accesses across it. Sufficient for
// intra-wave producer/consumer through LDS (single instruction stream).
__device__ __forceinline__ void wave_lds_fence() {
    asm volatile("s_waitcnt lgkmcnt(0)" ::: "memory");
}

__global__ __launch_bounds__(256) void pdf_resample_kernel(
    const float* __restrict__ weights,
    const float* __restrict__ ts,
    float* __restrict__ out,
    int num_rows)
{
    __shared__ float s_cdf[4][64];
    __shared__ float s_tsb[4][65];    // [64] = +INF sentinel
    __shared__ float s_nts[4][129];   // [128] = +INF sentinel
    __shared__ float s_out[4][192];

    const int lane = threadIdx.x & 63;
    const int wid  = threadIdx.x >> 6;
    const int row  = blockIdx.x * 4 + wid;
    if (row >= num_rows) return;   // safe: no block-wide barriers used

    const float* __restrict__ wrow = weights + (size_t)row * 64;
    const float* __restrict__ trow = ts      + (size_t)row * 64;

    const float w = wrow[lane];   // coalesced dword
    const float t = trow[lane];

    // ---- wsum over first 63 weights (lane 63 excluded) ----
    const float wc = (lane < 63) ? w : 0.0f;
    float s = wc;
    #pragma unroll
    for (int off = 32; off >= 1; off >>= 1)
        s += __shfl_xor(s, off, 64);
    const float wsum0   = s;
    const float padding = fmaxf(EPSF - wsum0, 0.0f);
    const float pdf = (lane < 63)
        ? (wc + padding * (1.0f / 63.0f)) / (wsum0 + padding)
        : 0.0f;

    // ---- inclusive prefix-sum of pdf across lanes ----
    float x = pdf;
    #pragma unroll
    for (int off = 1; off < 64; off <<= 1) {
        float y = __shfl_up(x, off, 64);
        if (lane >= off) x += y;
    }
    const float cv = fminf(x, 1.0f);

    // cdf[0] = 0; cdf[k] = min(1, scan[k-1]) for k=1..63
    float* cdf = s_cdf[wid];
    float* tsl = s_tsb[wid];
    cdf[(lane + 1) & 63] = (lane == 63) ? 0.0f : cv;
    tsl[lane] = t;
    if (lane == 0) tsl[64] = FINF;   // sentinel for fixed-count upper_bound
    wave_lds_fence();

    // ---- inverse-CDF sample: 2 u-values per lane ----
    float nv0, nv1;
    #pragma unroll
    for (int k = 0; k < 2; ++k) {
        const int   j = lane + 64 * k;
        const float u = (float)j / 127.0f;

        // largest i in [0,63] with cdf[i] <= u  (cdf[0]=0 <= u always;
        // 64 outcomes -> 6 steps is exact for this step-descent form)
        int i = 0;
        if (cdf[i + 32] <= u) i += 32;
        if (cdf[i + 16] <= u) i += 16;
        if (cdf[i +  8] <= u) i += 8;
        if (cdf[i +  4] <= u) i += 4;
        if (cdf[i +  2] <= u) i += 2;
        if (cdf[i +  1] <= u) i += 1;
        // searchsorted(..., side='right') => idx = i+1
        const int below = i;
        const int above = (i < 63) ? i + 1 : 63;   // min(63, idx)

        const float cb = cdf[below];
        const float ca = cdf[above];
        const float tb = tsl[below];
        const float ta = tsl[above];
        float denom = ca - cb;
        denom = (denom < EPSF) ? 1.0f : denom;
        const float tt = (u - cb) / denom;
        const float nt = tb + tt * (ta - tb);
        if (k == 0) nv0 = nt; else nv1 = nt;
    }

    // ---- enforce monotonicity (ulp-level fma noise) via max-scan ----
    float m0 = nv0;
    #pragma unroll
    for (int off = 1; off < 64; off <<= 1) {
        float y = __shfl_up(m0, off, 64);
        if (lane >= off) m0 = fmaxf(m0, y);
    }
    const float carry = __shfl(m0, 63, 64);
    float m1 = nv1;
    #pragma unroll
    for (int off = 1; off < 64; off <<= 1) {
        float y = __shfl_up(m1, off, 64);
        if (lane >= off) m1 = fmaxf(m1, y);
    }
    m1 = fmaxf(m1, carry);

    float* nts = s_nts[wid];
    nts[lane]      = m0;
    nts[lane + 64] = m1;
    if (lane == 0) nts[128] = FINF;  // sentinel for fixed-count lower_bound
    wave_lds_fence();

    // ---- merge ranks: ts[i] -> i + #{nts < ts[i]};  nts[j] -> j + #{ts <= nts[j]} ----
    // lower_bound over nts: 129 possible results -> 8 iterations.
    // After early convergence (lo==hi), reads hit nts[lo] (>= t) or the
    // +INF sentinel at [128]; state provably unchanged -> no OOB.
    int lo = 0, hi = 128;
    #pragma unroll
    for (int it = 0; it < 8; ++it) {
        const int mid = (lo + hi) >> 1;
        if (nts[mid] < t) lo = mid + 1; else hi = mid;
    }
    const int pos_t = lane + lo;

    // upper_bound over tsl: 65 possible results -> 7 iterations (sentinel at [64]).
    int lo0 = 0, hi0 = 64;
    int lo1 = 0, hi1 = 64;
    #pragma unroll
    for (int it = 0; it < 7; ++it) {
        const int mid0 = (lo0 + hi0) >> 1;
        if (tsl[mid0] <= m0) lo0 = mid0 + 1; else hi0 = mid0;
        const int mid1 = (lo1 + hi1) >> 1;
        if (tsl[mid1] <= m1) lo1 = mid1 + 1; else hi1 = mid1;
    }
    const int pos0 = lane + lo0;
    const int pos1 = lane + 64 + lo1;

    float* o = s_out[wid];
    o[pos_t] = t;
    o[pos0]  = m0;
    o[pos1]  = m1;
    wave_lds_fence();

    // ---- coalesced output: 3 dwords/lane ----
    float* __restrict__ orow = out + (size_t)row * 192;
    orow[lane]       = o[lane];
    orow[lane + 64]  = o[lane + 64];
    orow[lane + 128] = o[lane + 128];
}

extern "C" void kernel_launch(void* const* d_in, const int* in_sizes, int n_in,
                              void* d_out, int out_size, void* d_ws, size_t ws_size,
                              hipStream_t stream) {
    const float* weights = (const float*)d_in[0];
    const float* ts      = (const float*)d_in[1];
    float* out           = (float*)d_out;
    const int num_rows = in_sizes[0] / 64;     // 524288
    const int blocks   = (num_rows + 3) / 4;   // 4 waves/block, 1 row/wave
    pdf_resample_kernel<<<blocks, 256, 0, stream>>>(weights, ts, out, num_rows);
}

// Round 3
// 220.172 us; speedup vs baseline: 1.4209x; 1.4209x over previous
//
#include <hip/hip_runtime.h>

#define EPSF 1e-5f
#define FINF __builtin_huge_valf()

__device__ __forceinline__ void wave_lds_fence() {
    asm volatile("s_waitcnt lgkmcnt(0)" ::: "memory");
}

// DPP move with old=0 (identity for add/max over nonneg values).
#define DPPI(x, ctrl, rmask) \
    __builtin_amdgcn_update_dpp(0, (x), (ctrl), (rmask), 0xf, false)
#define DPPF(x, ctrl, rmask) \
    __builtin_bit_cast(float, __builtin_amdgcn_update_dpp(0, __builtin_bit_cast(int, (x)), (ctrl), (rmask), 0xf, false))

// Classic GCN wave64 inclusive scans: row_shr 1/2/4/8, then row_bcast:15
// (rows 1,3) and row_bcast:31 (rows 2,3). Pure VALU, zero DS-pipe ops.
__device__ __forceinline__ float wscan_add_f(float x) {
    x += DPPF(x, 0x111, 0xf);
    x += DPPF(x, 0x112, 0xf);
    x += DPPF(x, 0x114, 0xf);
    x += DPPF(x, 0x118, 0xf);
    x += DPPF(x, 0x142, 0xa);
    x += DPPF(x, 0x143, 0xc);
    return x;
}
__device__ __forceinline__ float wscan_max_f(float x) {
    x = fmaxf(x, DPPF(x, 0x111, 0xf));
    x = fmaxf(x, DPPF(x, 0x112, 0xf));
    x = fmaxf(x, DPPF(x, 0x114, 0xf));
    x = fmaxf(x, DPPF(x, 0x118, 0xf));
    x = fmaxf(x, DPPF(x, 0x142, 0xa));
    x = fmaxf(x, DPPF(x, 0x143, 0xc));
    return x;
}
__device__ __forceinline__ int wscan_max_i(int x) {
    int y;
    y = DPPI(x, 0x111, 0xf); x = (x > y) ? x : y;
    y = DPPI(x, 0x112, 0xf); x = (x > y) ? x : y;
    y = DPPI(x, 0x114, 0xf); x = (x > y) ? x : y;
    y = DPPI(x, 0x118, 0xf); x = (x > y) ? x : y;
    y = DPPI(x, 0x142, 0xa); x = (x > y) ? x : y;
    y = DPPI(x, 0x143, 0xc); x = (x > y) ? x : y;
    return x;
}
__device__ __forceinline__ float readlane_f(float x, int l) {
    return __builtin_bit_cast(float, __builtin_amdgcn_readlane(__builtin_bit_cast(int, x), l));
}

__global__ __launch_bounds__(256) void pdf_resample_kernel(
    const float* __restrict__ weights,
    const float* __restrict__ ts,
    float* __restrict__ out,
    int num_rows)
{
    // Per-wave slices; no __syncthreads anywhere (wave-private producer/consumer).
    __shared__ float4 s_pack[4][64];   // (cdf[i], ts[i], cdf[i+1], ts[i+1])
    __shared__ int    s_A[4][130];     // sample-bin scatter array
    __shared__ float  s_nts[4][130];   // sorted new_ts + INF sentinel
    __shared__ int    s_B[4][130];     // merge-rank scatter array

    const int lane = threadIdx.x & 63;
    const int wid  = threadIdx.x >> 6;
    const int row  = blockIdx.x * 4 + wid;
    if (row >= num_rows) return;

    const float w = weights[(size_t)row * 64 + lane];
    const float t = ts[(size_t)row * 64 + lane];

    // ---- cdf via one DPP add-scan (wsum = lane63 of scan; no reduction) ----
    const float wc = (lane < 63) ? w : 0.0f;
    const float sw = wscan_add_f(wc);
    const float wsum0   = readlane_f(sw, 63);          // sum of w[0..62]
    const float padding = fmaxf(EPSF - wsum0, 0.0f);
    const float pad63   = padding * (1.0f / 63.0f);
    const float rden    = 1.0f / (wsum0 + padding);

    // cv = cdf[lane+1] (valid for lane 0..62)
    const float cv = fminf(1.0f, (sw + (float)(lane + 1) * pad63) * rden);
    float cdf_lo = __shfl_up(cv, 1, 64);
    if (lane == 0) cdf_lo = 0.0f;                      // cdf[0] = 0
    const float cdf_hi = (lane == 63) ? cdf_lo : cv;   // bin63: ca=cb=cdf[63]
    float ts_hi = __shfl_down(t, 1, 64);
    if (lane == 63) ts_hi = t;                         // bin63: ta=tb=ts[63]

    float4* pack = s_pack[wid];
    pack[lane] = make_float4(cdf_lo, t, cdf_hi, ts_hi);

    int* A = s_A[wid];
    A[lane]      = 0;
    A[lane + 64] = 0;

    // ---- exact r = #{ j in [0,128): u_j < cdf[lane] }, u_j = j*fl(1/127) ----
    const float C127 = 1.0f / 127.0f;                  // constant-folded
    const float est  = cdf_lo * 127.0f;
    int base = (int)est - 2;
    base = (base < 0) ? 0 : ((base > 128) ? 128 : base);
    int r = base;
    #pragma unroll
    for (int d = 0; d < 5; ++d) {                      // drift window provably <= +-2
        const int j = base + d;
        if (j < 128 && (float)j * C127 < cdf_lo) r = j + 1;
    }
    const int r_next = __shfl_down(r, 1, 64);
    if ((lane == 63) || (r_next > r)) A[r] = lane;     // last k with this r wins
    wave_lds_fence();

    // i_j = max{k: r_k <= j} = max{k: cdf[k] <= u_j}  (bit-exact searchsorted)
    const int a0 = A[lane];
    const int a1 = A[lane + 64];
    int i0 = wscan_max_i(a0);
    const int carryA = __builtin_amdgcn_readlane(i0, 63);
    int t1 = wscan_max_i(a1);
    int i1 = (t1 > carryA) ? t1 : carryA;

    // ---- interpolate 2 samples (1 ds_read_b128 each) ----
    const float u0 = (float)lane * C127;
    const float u1 = (float)(lane + 64) * C127;
    const float4 p0 = pack[i0];
    const float4 p1 = pack[i1];
    float d0 = p0.z - p0.x; d0 = (d0 < EPSF) ? 1.0f : d0;
    float d1 = p1.z - p1.x; d1 = (d1 < EPSF) ? 1.0f : d1;
    float nt0 = p0.y + ((u0 - p0.x) / d0) * (p0.w - p0.y);
    float nt1 = p1.y + ((u1 - p1.x) / d1) * (p1.w - p1.y);

    // ---- monotone guard (ulp-level) via DPP max-scans; keeps merge bijective ----
    nt0 = wscan_max_f(nt0);
    const float carryN = readlane_f(nt0, 63);
    nt1 = fmaxf(wscan_max_f(nt1), carryN);

    float* nts = s_nts[wid];
    nts[lane]      = nt0;
    nts[lane + 64] = nt1;
    if (lane == 0) nts[128] = FINF;                    // search sentinel
    int* B = s_B[wid];
    B[lane]      = 0;
    B[lane + 64] = 0;
    wave_lds_fence();

    // ---- s = #{ nts < t } : 8-iter lower_bound (proven in R2) ----
    int lo = 0, hi = 128;
    #pragma unroll
    for (int it = 0; it < 8; ++it) {
        const int mid = (lo + hi) >> 1;
        if (nts[mid] < t) lo = mid + 1; else hi = mid;
    }
    const int s = lo;
    const int s_next = __shfl_down(s, 1, 64);
    if ((lane == 63) || (s_next > s)) B[s] = lane + 1; // store i+1; q=0 default
    wave_lds_fence();

    // q_j = #{ i : s_i <= j }  ( == #{ i : ts_i <= nts_j } )
    const int b0 = B[lane];
    const int b1 = B[lane + 64];
    int q0 = wscan_max_i(b0);
    const int carryB = __builtin_amdgcn_readlane(q0, 63);
    int t2 = wscan_max_i(b1);
    int q1 = (t2 > carryB) ? t2 : carryB;

    // ---- direct global scatter (positions are a permutation of [0,192)) ----
    float* __restrict__ orow = out + (size_t)row * 192;
    orow[lane + s]        = t;
    orow[lane + q0]       = nt0;
    orow[lane + 64 + q1]  = nt1;
}

extern "C" void kernel_launch(void* const* d_in, const int* in_sizes, int n_in,
                              void* d_out, int out_size, void* d_ws, size_t ws_size,
                              hipStream_t stream) {
    const float* weights = (const float*)d_in[0];
    const float* ts      = (const float*)d_in[1];
    float* out           = (float*)d_out;
    const int num_rows = in_sizes[0] / 64;     // 524288
    const int blocks   = (num_rows + 3) / 4;   // 4 waves/block, 1 row/wave
    pdf_resample_kernel<<<blocks, 256, 0, stream>>>(weights, ts, out, num_rows);
}

// Round 4
// 164.129 us; speedup vs baseline: 1.9060x; 1.3415x over previous
//
#include <hip/hip_runtime.h>

#define EPSF 1e-5f

__device__ __forceinline__ void wave_lds_fence() {
    asm volatile("s_waitcnt lgkmcnt(0)" ::: "memory");
}

// DPP move with old=0 (identity for add/max over nonnegative values).
#define DPPI(x, ctrl, rmask) \
    __builtin_amdgcn_update_dpp(0, (x), (ctrl), (rmask), 0xf, false)
#define DPPF(x, ctrl, rmask) \
    __builtin_bit_cast(float, __builtin_amdgcn_update_dpp(0, __builtin_bit_cast(int, (x)), (ctrl), (rmask), 0xf, false))

// GCN wave64 inclusive scans: row_shr 1/2/4/8 + row_bcast:15 (rows 1,3) +
// row_bcast:31 (rows 2,3). Pure VALU. (Proven correct in R3.)
__device__ __forceinline__ float wscan_add_f(float x) {
    x += DPPF(x, 0x111, 0xf);
    x += DPPF(x, 0x112, 0xf);
    x += DPPF(x, 0x114, 0xf);
    x += DPPF(x, 0x118, 0xf);
    x += DPPF(x, 0x142, 0xa);
    x += DPPF(x, 0x143, 0xc);
    return x;
}
__device__ __forceinline__ int wscan_max_i(int x) {
    int y;
    y = DPPI(x, 0x111, 0xf); x = (x > y) ? x : y;
    y = DPPI(x, 0x112, 0xf); x = (x > y) ? x : y;
    y = DPPI(x, 0x114, 0xf); x = (x > y) ? x : y;
    y = DPPI(x, 0x118, 0xf); x = (x > y) ? x : y;
    y = DPPI(x, 0x142, 0xa); x = (x > y) ? x : y;
    y = DPPI(x, 0x143, 0xc); x = (x > y) ? x : y;
    return x;
}
__device__ __forceinline__ float readlane_f(float x, int l) {
    return __builtin_bit_cast(float, __builtin_amdgcn_readlane(__builtin_bit_cast(int, x), l));
}

__global__ __launch_bounds__(256) void pdf_resample_kernel(
    const float* __restrict__ weights,
    const float* __restrict__ ts,
    float* __restrict__ out,
    int num_rows)
{
    // Per-wave slices; no __syncthreads (wave-private producer/consumer).
    __shared__ float4 s_pack[4][64];   // (cdf[i], ts[i], cdf[i+1], ts[i+1])
    __shared__ int    s_A[4][129];     // sample-bin scatter (r can be 128)
    __shared__ int    s_C[4][65];      // merge-rank scatter (q in [1,64])

    const int lane = threadIdx.x & 63;
    const int wid  = threadIdx.x >> 6;
    const int row  = blockIdx.x * 4 + wid;
    if (row >= num_rows) return;

    const float w = weights[(size_t)row * 64 + lane];
    const float t = ts[(size_t)row * 64 + lane];

    // ---- cdf via one DPP add-scan; wsum = lane63 of scan ----
    const float wc = (lane < 63) ? w : 0.0f;
    const float sw = wscan_add_f(wc);
    const float wsum0   = readlane_f(sw, 63);
    const float padding = fmaxf(EPSF - wsum0, 0.0f);
    const float pad63   = padding * (1.0f / 63.0f);
    const float rden    = __builtin_amdgcn_rcpf(wsum0 + padding);

    // cv = cdf[lane+1] for lanes 0..62; cdf monotone (all terms monotone).
    const float cv = fminf(1.0f, (sw + (float)(lane + 1) * pad63) * rden);
    float cdf_lo = __shfl_up(cv, 1, 64);
    if (lane == 0) cdf_lo = 0.0f;                      // cdf[0] = 0
    const float cdf_hi = (lane == 63) ? cdf_lo : cv;   // bin63: ca=cb
    float ts_hi = __shfl_down(t, 1, 64);
    if (lane == 63) ts_hi = t;                         // bin63: ta=tb

    float4* pack = s_pack[wid];
    int*    A    = s_A[wid];
    int*    C    = s_C[wid];
    pack[lane] = make_float4(cdf_lo, t, cdf_hi, ts_hi);
    A[lane]      = 0;
    A[lane + 64] = 0;
    C[lane]      = 0;
    if (lane == 0) C[64] = 0;

    // ---- exact r = #{ j in [0,128): u_j < cdf[lane] }, u_j = j*fl(1/127) ----
    const float C127 = 1.0f / 127.0f;
    int base = (int)(cdf_lo * 127.0f) - 2;             // drift window +-2 proven
    base = (base < 0) ? 0 : base;                      // base <= 125 by cdf<=1
    int r = base;
    #pragma unroll
    for (int d = 0; d < 5; ++d) {
        const int j = base + d;
        if (j < 128 && (float)j * C127 < cdf_lo) r = j + 1;
    }
    // r in [0,128]; A[128] write is harmless (never read).
    const int r_next = __shfl_down(r, 1, 64);
    if ((lane == 63) || (r_next > r)) A[r] = lane;     // last k of each r-run
    wave_lds_fence();

    // i_j = max{k: r_k <= j} == max{k: cdf[k] <= u_j} (bit-exact searchsorted)
    int i0 = wscan_max_i(A[lane]);
    const int carryA = __builtin_amdgcn_readlane(i0, 63);
    int i1 = wscan_max_i(A[lane + 64]);
    i1 = (i1 > carryA) ? i1 : carryA;

    // ---- interpolate 2 samples (1 ds_read_b128 each) ----
    const float u0 = (float)lane * C127;
    const float u1 = (float)(lane + 64) * C127;
    const float4 p0 = pack[i0];
    const float4 p1 = pack[i1];
    float d0 = p0.z - p0.x; d0 = (d0 < EPSF) ? 1.0f : d0;
    float d1 = p1.z - p1.x; d1 = (d1 < EPSF) ? 1.0f : d1;
    const float nt0 = p0.y + ((u0 - p0.x) * __builtin_amdgcn_rcpf(d0)) * (p0.w - p0.y);
    const float nt1 = p1.y + ((u1 - p1.x) * __builtin_amdgcn_rcpf(d1)) * (p1.w - p1.y);

    // ---- merge rank q_j = #{i: ts_i <= nts_j}, derived from the bin ----
    // nts_j in [ts_bel, ts_abv]; q = bel+1 (+1 if nt reached ts_abv).
    // q is monotone in j: within-bin nt monotone; across-bin q_{j+1}>=bel'+1>=q_j.
    const int q0 = i0 + 1 + ((i0 < 63 && nt0 >= p0.w) ? 1 : 0);
    const int q1 = i1 + 1 + ((i1 < 63 && nt1 >= p1.w) ? 1 : 0);

    // scatter C[q_j] = j+1 for the LAST j of each q-run (spans both halves)
    int q0n = __shfl_down(q0, 1, 64);
    const int q1first = __builtin_amdgcn_readlane(q1, 0);
    if (lane == 63) q0n = q1first;
    if (q0n > q0) C[q0] = lane + 1;
    const int q1n = __shfl_down(q1, 1, 64);
    if ((lane == 63) || (q1n > q1)) C[q1] = lane + 65;
    wave_lds_fence();

    // s_i = #{j: q_j <= i} = max-scan of C[0..i]  (== #{j: nts_j < t_i})
    const int s = wscan_max_i(C[lane]);

    // ---- direct global scatter (positions form a permutation of [0,192)) ----
    float* __restrict__ orow = out + (size_t)row * 192;
    orow[lane + s]       = t;
    orow[lane + q0]      = nt0;
    orow[lane + 64 + q1] = nt1;
}

extern "C" void kernel_launch(void* const* d_in, const int* in_sizes, int n_in,
                              void* d_out, int out_size, void* d_ws, size_t ws_size,
                              hipStream_t stream) {
    const float* weights = (const float*)d_in[0];
    const float* ts      = (const float*)d_in[1];
    float* out           = (float*)d_out;
    const int num_rows = in_sizes[0] / 64;     // 524288
    const int blocks   = (num_rows + 3) / 4;   // 4 waves/block, 1 row/wave
    pdf_resample_kernel<<<blocks, 256, 0, stream>>>(weights, ts, out, num_rows);
}

// Round 5
// 161.415 us; speedup vs baseline: 1.9381x; 1.0168x over previous
//
#include <hip/hip_runtime.h>

#define EPSF 1e-5f

__device__ __forceinline__ void wave_lds_fence() {
    asm volatile("s_waitcnt lgkmcnt(0)" ::: "memory");
}

// DPP move with old=0 (identity for add/max over nonnegative values; also
// provides the 0 boundary value for wave shifts).
#define DPPI(x, ctrl, rmask) \
    __builtin_amdgcn_update_dpp(0, (x), (ctrl), (rmask), 0xf, false)
#define DPPF(x, ctrl, rmask) \
    __builtin_bit_cast(float, __builtin_amdgcn_update_dpp(0, __builtin_bit_cast(int, (x)), (ctrl), (rmask), 0xf, false))

// Wave-wide shift-by-1 via gfx9 DPP (no DS pipe): lane i <- lane i-1 (shr)
// or lane i <- lane i+1 (shl); out-of-range lane reads old=0.
__device__ __forceinline__ float dpp_up1_f(float x) { return DPPF(x, 0x138, 0xf); }
__device__ __forceinline__ float dpp_dn1_f(float x) { return DPPF(x, 0x130, 0xf); }
__device__ __forceinline__ int   dpp_dn1_i(int   x) { return DPPI(x, 0x130, 0xf); }

// GCN wave64 inclusive scans: row_shr 1/2/4/8 + row_bcast:15 (rows 1,3) +
// row_bcast:31 (rows 2,3). Pure VALU. (Proven R3/R4.)
__device__ __forceinline__ float wscan_add_f(float x) {
    x += DPPF(x, 0x111, 0xf);
    x += DPPF(x, 0x112, 0xf);
    x += DPPF(x, 0x114, 0xf);
    x += DPPF(x, 0x118, 0xf);
    x += DPPF(x, 0x142, 0xa);
    x += DPPF(x, 0x143, 0xc);
    return x;
}
__device__ __forceinline__ int wscan_max_i(int x) {
    int y;
    y = DPPI(x, 0x111, 0xf); x = (x > y) ? x : y;
    y = DPPI(x, 0x112, 0xf); x = (x > y) ? x : y;
    y = DPPI(x, 0x114, 0xf); x = (x > y) ? x : y;
    y = DPPI(x, 0x118, 0xf); x = (x > y) ? x : y;
    y = DPPI(x, 0x142, 0xa); x = (x > y) ? x : y;
    y = DPPI(x, 0x143, 0xc); x = (x > y) ? x : y;
    return x;
}
__device__ __forceinline__ float readlane_f(float x, int l) {
    return __builtin_bit_cast(float, __builtin_amdgcn_readlane(__builtin_bit_cast(int, x), l));
}

__global__ __launch_bounds__(256) void pdf_resample_kernel(
    const float* __restrict__ weights,
    const float* __restrict__ ts,
    float* __restrict__ out,
    int num_rows)
{
    // Per-wave slices; no __syncthreads (wave-private producer/consumer).
    __shared__ float4 s_pack[4][64];   // (cdf[i], ts[i], cdf[i+1], ts[i+1])
    __shared__ int    s_A[4][130];     // interleaved sample-bin scatter array
    __shared__ int    s_C[4][65];      // merge-rank scatter (q in [1,64])

    const int lane = threadIdx.x & 63;
    const int wid  = threadIdx.x >> 6;
    const int row  = blockIdx.x * 4 + wid;
    if (row >= num_rows) return;

    const float w = weights[(size_t)row * 64 + lane];
    const float t = ts[(size_t)row * 64 + lane];

    // ---- cdf via one DPP add-scan; wsum = lane63 of scan ----
    const float wc = (lane < 63) ? w : 0.0f;
    const float sw = wscan_add_f(wc);
    const float wsum0   = readlane_f(sw, 63);
    const float padding = fmaxf(EPSF - wsum0, 0.0f);
    const float pad63   = padding * (1.0f / 63.0f);
    const float rden    = __builtin_amdgcn_rcpf(wsum0 + padding);

    // cv = cdf[lane+1] for lanes 0..62; monotone in lane.
    const float cv = fminf(1.0f, (sw + (float)(lane + 1) * pad63) * rden);
    const float cdf_lo = dpp_up1_f(cv);                // lane0 -> 0 via old=0
    const float cdf_hi = (lane == 63) ? cdf_lo : cv;   // bin63: ca=cb
    float ts_hi = dpp_dn1_f(t);
    if (lane == 63) ts_hi = t;                         // bin63: ta=tb

    float4* pack = s_pack[wid];
    int*    A    = s_A[wid];
    int*    C    = s_C[wid];
    pack[lane] = make_float4(cdf_lo, t, cdf_hi, ts_hi);
    ((int2*)A)[lane] = make_int2(0, 0);   // inits interleaved slots 0..127
    C[lane] = 0;                          // C[64] is written-only; no init

    // ---- exact r = #{ j in [0,128): u_j < cdf[lane] }, u_j = j*fl(1/127) ----
    const float C127 = 1.0f / 127.0f;
    int base = (int)(cdf_lo * 127.0f) - 2;             // drift window +-2 proven
    base = (base < 0) ? 0 : base;
    int r = base;
    #pragma unroll
    for (int d = 0; d < 5; ++d) {
        const int j = base + d;
        if (j < 128 && (float)j * C127 < cdf_lo) r = j + 1;
    }
    // Interleaved layout: A'[2r] for r<64, A'[2r-127] for r>=64 (r=128 -> 129,
    // allocated, never read). Injective in r, so dedup-last-of-run still holds.
    const int mr = (r < 64) ? (2 * r) : (2 * r - 127);
    const int r_next = dpp_dn1_i(r);                   // lane63 -> 0, handled below
    if ((lane == 63) || (r_next > r)) A[mr] = lane;    // last k of each r-run
    wave_lds_fence();

    // i_j = max{k: r_k <= j} == max{k: cdf[k] <= u_j} (bit-exact searchsorted);
    // one b64 read gives both halves: av.x = old A[lane], av.y = old A[lane+64].
    const int2 av = ((const int2*)A)[lane];
    int i0 = wscan_max_i(av.x);
    const int carryA = __builtin_amdgcn_readlane(i0, 63);
    int i1 = wscan_max_i(av.y);
    i1 = (i1 > carryA) ? i1 : carryA;

    // ---- interpolate 2 samples (1 ds_read_b128 each) ----
    const float u0 = (float)lane * C127;
    const float u1 = (float)(lane + 64) * C127;
    const float4 p0 = pack[i0];
    const float4 p1 = pack[i1];
    float d0 = p0.z - p0.x; d0 = (d0 < EPSF) ? 1.0f : d0;
    float d1 = p1.z - p1.x; d1 = (d1 < EPSF) ? 1.0f : d1;
    const float nt0 = p0.y + ((u0 - p0.x) * __builtin_amdgcn_rcpf(d0)) * (p0.w - p0.y);
    const float nt1 = p1.y + ((u1 - p1.x) * __builtin_amdgcn_rcpf(d1)) * (p1.w - p1.y);

    // ---- merge rank q_j = #{i: ts_i <= nts_j}, derived from the bin ----
    // (monotone in j: within-bin interp monotone; across-bin q jump >= 0)
    const int q0 = i0 + 1 + ((i0 < 63 && nt0 >= p0.w) ? 1 : 0);
    const int q1 = i1 + 1 + ((i1 < 63 && nt1 >= p1.w) ? 1 : 0);

    // scatter C[q_j] = j+1 for the LAST j of each q-run (spans both halves)
    int q0n = dpp_dn1_i(q0);
    const int q1first = __builtin_amdgcn_readlane(q1, 0);
    if (lane == 63) q0n = q1first;
    if (q0n > q0) C[q0] = lane + 1;
    const int q1n = dpp_dn1_i(q1);
    if ((lane == 63) || (q1n > q1)) C[q1] = lane + 65;
    wave_lds_fence();

    // s_i = #{j: q_j <= i} = max-scan of C[0..i]  (== #{j: nts_j < t_i})
    const int s = wscan_max_i(C[lane]);

    // ---- direct global scatter (positions form a permutation of [0,192)) ----
    float* __restrict__ orow = out + (size_t)row * 192;
    orow[lane + s]       = t;
    orow[lane + q0]      = nt0;
    orow[lane + 64 + q1] = nt1;
}

extern "C" void kernel_launch(void* const* d_in, const int* in_sizes, int n_in,
                              void* d_out, int out_size, void* d_ws, size_t ws_size,
                              hipStream_t stream) {
    const float* weights = (const float*)d_in[0];
    const float* ts      = (const float*)d_in[1];
    float* out           = (float*)d_out;
    const int num_rows = in_sizes[0] / 64;     // 524288
    const int blocks   = (num_rows + 3) / 4;   // 4 waves/block, 1 row/wave
    pdf_resample_kernel<<<blocks, 256, 0, stream>>>(weights, ts, out, num_rows);
}

// Round 6
// 139.626 us; speedup vs baseline: 2.2405x; 1.1561x over previous
//
#include <hip/hip_runtime.h>

#define EPSF 1e-5f

__device__ __forceinline__ void wave_lds_fence() {
    asm volatile("s_waitcnt lgkmcnt(0)" ::: "memory");
}

// DPP move with old=0 (identity for add/max over nonnegative values; also
// provides the 0 boundary value for wave shifts).
#define DPPI(x, ctrl, rmask) \
    __builtin_amdgcn_update_dpp(0, (x), (ctrl), (rmask), 0xf, false)
#define DPPF(x, ctrl, rmask) \
    __builtin_bit_cast(float, __builtin_amdgcn_update_dpp(0, __builtin_bit_cast(int, (x)), (ctrl), (rmask), 0xf, false))

// Wave-wide shift-by-1 via gfx9 DPP (no DS pipe).
__device__ __forceinline__ float dpp_up1_f(float x) { return DPPF(x, 0x138, 0xf); }
__device__ __forceinline__ float dpp_dn1_f(float x) { return DPPF(x, 0x130, 0xf); }
__device__ __forceinline__ int   dpp_dn1_i(int   x) { return DPPI(x, 0x130, 0xf); }

// GCN wave64 inclusive scans: row_shr 1/2/4/8 + row_bcast:15 (rows 1,3) +
// row_bcast:31 (rows 2,3). Pure VALU. (Proven R3-R5.)
__device__ __forceinline__ float wscan_add_f(float x) {
    x += DPPF(x, 0x111, 0xf);
    x += DPPF(x, 0x112, 0xf);
    x += DPPF(x, 0x114, 0xf);
    x += DPPF(x, 0x118, 0xf);
    x += DPPF(x, 0x142, 0xa);
    x += DPPF(x, 0x143, 0xc);
    return x;
}
__device__ __forceinline__ int wscan_max_i(int x) {
    int y;
    y = DPPI(x, 0x111, 0xf); x = (x > y) ? x : y;
    y = DPPI(x, 0x112, 0xf); x = (x > y) ? x : y;
    y = DPPI(x, 0x114, 0xf); x = (x > y) ? x : y;
    y = DPPI(x, 0x118, 0xf); x = (x > y) ? x : y;
    y = DPPI(x, 0x142, 0xa); x = (x > y) ? x : y;
    y = DPPI(x, 0x143, 0xc); x = (x > y) ? x : y;
    return x;
}
__device__ __forceinline__ float readlane_f(float x, int l) {
    return __builtin_bit_cast(float, __builtin_amdgcn_readlane(__builtin_bit_cast(int, x), l));
}

__global__ __launch_bounds__(256) void pdf_resample_kernel(
    const float* __restrict__ weights,
    const float* __restrict__ ts,
    float* __restrict__ out,
    int num_rows)
{
    // Per-wave slices; no __syncthreads (wave-private producer/consumer).
    __shared__ float4 s_pack[4][64];   // (cdf[i], ts[i], cdf[i+1], ts[i+1])
    __shared__ int    s_A[4][130];     // interleaved sample-bin scatter array

    const int lane = threadIdx.x & 63;
    const int wid  = threadIdx.x >> 6;
    const int row  = blockIdx.x * 4 + wid;
    if (row >= num_rows) return;

    const float w = weights[(size_t)row * 64 + lane];
    const float t = ts[(size_t)row * 64 + lane];

    // ---- cdf via one DPP add-scan; wsum = lane63 of scan ----
    const float wc = (lane < 63) ? w : 0.0f;
    const float sw = wscan_add_f(wc);
    const float wsum0   = readlane_f(sw, 63);
    const float padding = fmaxf(EPSF - wsum0, 0.0f);
    const float pad63   = padding * (1.0f / 63.0f);
    const float rden    = __builtin_amdgcn_rcpf(wsum0 + padding);

    const float flane = (float)lane;                   // exact, reused 3x
    // cv = cdf[lane+1] for lanes 0..62; monotone in lane.
    const float cv = fminf(1.0f, fmaf(flane + 1.0f, pad63, sw) * rden);
    const float cdf_lo = dpp_up1_f(cv);                // lane0 -> 0 via old=0
    const float cdf_hi = (lane == 63) ? cdf_lo : cv;   // bin63 degenerate: ca=cb
    float ts_hi = dpp_dn1_f(t);
    if (lane == 63) ts_hi = t;                         // bin63: ta=tb

    float4* pack = s_pack[wid];
    int*    A    = s_A[wid];
    pack[lane] = make_float4(cdf_lo, t, cdf_hi, ts_hi);
    ((int2*)A)[lane] = make_int2(0, 0);                // init slots 0..127

    // ---- exact r = #{ j in [0,128): fl(j*C127) < cdf_lo } ----
    // est = cdf_lo*127 has rel err <= 2^-24 -> true r in {base, base+1, base+2}.
    const float C127 = 1.0f / 127.0f;
    int base = (int)(cdf_lo * 127.0f);
    base = (base < 0) ? 0 : ((base > 125) ? 125 : base);
    int r = base;
    #pragma unroll
    for (int d = 0; d < 3; ++d) {
        const int j = base + d;                        // j <= 127
        if ((float)j * C127 < cdf_lo) r = j + 1;
    }

    // Interleaved dedup-scatter: A'[2r] for r<64, A'[2r-127] for r>=64
    // (r=128 -> slot 129: allocated, never read). Injective in r.
    const int mr = (r < 64) ? (2 * r) : (2 * r - 127);
    const int r_next = dpp_dn1_i(r);                   // lane63 -> 0 (forced write)
    if ((lane == 63) || (r_next > r)) A[mr] = lane;    // last k of each r-run

    // ---- merge position of ts[lane]: s = r (proven identity: with t-first
    // tie order, #{j: nts_j before t_i} = #{j: i_j <= i-1} = #{j: j < r_i} = r_i).
    // Fire early: independent of everything below the fence.
    float* __restrict__ orow = out + (size_t)row * 192;
    orow[lane + r] = t;

    wave_lds_fence();

    // i_j = max{k: r_k <= j} == max{k: cdf[k] <= u_j} (bit-exact searchsorted);
    // one b64 read gives both halves.
    const int2 av = ((const int2*)A)[lane];
    int i0 = wscan_max_i(av.x);
    const int carryA = __builtin_amdgcn_readlane(i0, 63);
    int i1 = wscan_max_i(av.y);
    i1 = (i1 > carryA) ? i1 : carryA;

    // ---- interpolate 2 samples (1 ds_read_b128 each) ----
    const float u0 = flane * C127;
    const float u1 = (flane + 64.0f) * C127;
    const float4 p0 = pack[i0];
    const float4 p1 = pack[i1];
    float d0 = p0.z - p0.x; d0 = (d0 < EPSF) ? 1.0f : d0;
    float d1 = p1.z - p1.x; d1 = (d1 < EPSF) ? 1.0f : d1;
    const float nt0 = p0.y + ((u0 - p0.x) * __builtin_amdgcn_rcpf(d0)) * (p0.w - p0.y);
    const float nt1 = p1.y + ((u1 - p1.x) * __builtin_amdgcn_rcpf(d1)) * (p1.w - p1.y);

    // ---- merge positions of samples: j + i_j + 1 (t-first tie order) ----
    // Permutation of [0,192) guaranteed combinatorially (monotone r + inverse i).
    orow[lane + i0 + 1]      = nt0;
    orow[lane + 64 + i1 + 1] = nt1;
}

extern "C" void kernel_launch(void* const* d_in, const int* in_sizes, int n_in,
                              void* d_out, int out_size, void* d_ws, size_t ws_size,
                              hipStream_t stream) {
    const float* weights = (const float*)d_in[0];
    const float* ts      = (const float*)d_in[1];
    float* out           = (float*)d_out;
    const int num_rows = in_sizes[0] / 64;     // 524288
    const int blocks   = (num_rows + 3) / 4;   // 4 waves/block, 1 row/wave
    pdf_resample_kernel<<<blocks, 256, 0, stream>>>(weights, ts, out, num_rows);
}

// Round 7
// 136.140 us; speedup vs baseline: 2.2979x; 1.0256x over previous
//
#include <hip/hip_runtime.h>

#define EPSF 1e-5f

// DPP move with old=0 (identity for add/max over nonnegative values; also
// provides the 0 boundary value for wave shifts).
#define DPPI(x, ctrl, rmask) \
    __builtin_amdgcn_update_dpp(0, (x), (ctrl), (rmask), 0xf, false)
#define DPPF(x, ctrl, rmask) \
    __builtin_bit_cast(float, __builtin_amdgcn_update_dpp(0, __builtin_bit_cast(int, (x)), (ctrl), (rmask), 0xf, false))

// Wave-wide shift-by-1 via gfx9 DPP (no DS pipe).
__device__ __forceinline__ float dpp_up1_f(float x) { return DPPF(x, 0x138, 0xf); }
__device__ __forceinline__ float dpp_dn1_f(float x) { return DPPF(x, 0x130, 0xf); }
__device__ __forceinline__ int   dpp_dn1_i(int   x) { return DPPI(x, 0x130, 0xf); }

// GCN wave64 inclusive scans: row_shr 1/2/4/8 + row_bcast:15 (rows 1,3) +
// row_bcast:31 (rows 2,3). Pure VALU. (Proven R3-R6.)
__device__ __forceinline__ float wscan_add_f(float x) {
    x += DPPF(x, 0x111, 0xf);
    x += DPPF(x, 0x112, 0xf);
    x += DPPF(x, 0x114, 0xf);
    x += DPPF(x, 0x118, 0xf);
    x += DPPF(x, 0x142, 0xa);
    x += DPPF(x, 0x143, 0xc);
    return x;
}
__device__ __forceinline__ int wscan_max_i(int x) {
    int y;
    y = DPPI(x, 0x111, 0xf); x = (x > y) ? x : y;
    y = DPPI(x, 0x112, 0xf); x = (x > y) ? x : y;
    y = DPPI(x, 0x114, 0xf); x = (x > y) ? x : y;
    y = DPPI(x, 0x118, 0xf); x = (x > y) ? x : y;
    y = DPPI(x, 0x142, 0xa); x = (x > y) ? x : y;
    y = DPPI(x, 0x143, 0xc); x = (x > y) ? x : y;
    return x;
}
__device__ __forceinline__ float readlane_f(float x, int l) {
    return __builtin_bit_cast(float, __builtin_amdgcn_readlane(__builtin_bit_cast(int, x), l));
}

// 2 rows per wave: phase1(row0)+phase1(row1) -> one fence -> phase2(both).
// Independent per-row chains fill each other's dependency stalls (ILP),
// and fixed per-wave overhead amortizes 2x.
__global__ __launch_bounds__(256, 8) void pdf_resample_kernel(
    const float* __restrict__ weights,
    const float* __restrict__ ts,
    float* __restrict__ out,
    int num_rows)
{
    // Per-wave slices (2 rows/wave); no __syncthreads anywhere.
    __shared__ float4 s_pack[8][64];   // (cdf[i], ts[i], cdf[i+1], ts[i+1])
    __shared__ int    s_A[8][130];     // interleaved sample-bin scatter array

    const int lane = threadIdx.x & 63;
    const int wid  = threadIdx.x >> 6;
    const int row0 = (blockIdx.x * 4 + wid) * 2;
    if (row0 >= num_rows) return;      // num_rows is even -> row0+1 also valid

    const size_t g0 = (size_t)row0 * 64 + lane;
    const float w0 = weights[g0];
    const float t0 = ts[g0];
    const float w1 = weights[g0 + 64];
    const float t1 = ts[g0 + 64];

    float4* pack0 = s_pack[wid * 2];
    float4* pack1 = s_pack[wid * 2 + 1];
    int*    A0    = s_A[wid * 2];
    int*    A1    = s_A[wid * 2 + 1];

    const float flane = (float)lane;
    const float C127  = 1.0f / 127.0f;

    // ================= phase 1 (both rows, interleaved) =================
    const float wc0 = (lane < 63) ? w0 : 0.0f;
    const float wc1 = (lane < 63) ? w1 : 0.0f;
    const float sw0 = wscan_add_f(wc0);
    const float sw1 = wscan_add_f(wc1);

    const float wsumA = readlane_f(sw0, 63);
    const float wsumB = readlane_f(sw1, 63);
    const float padA  = fmaxf(EPSF - wsumA, 0.0f);
    const float padB  = fmaxf(EPSF - wsumB, 0.0f);
    const float p63A  = padA * (1.0f / 63.0f);
    const float p63B  = padB * (1.0f / 63.0f);
    const float rdenA = __builtin_amdgcn_rcpf(wsumA + padA);
    const float rdenB = __builtin_amdgcn_rcpf(wsumB + padB);

    // cv = cdf[lane+1]; monotone in lane.
    const float cv0 = fminf(1.0f, fmaf(flane + 1.0f, p63A, sw0) * rdenA);
    const float cv1 = fminf(1.0f, fmaf(flane + 1.0f, p63B, sw1) * rdenB);
    const float cdf_lo0 = dpp_up1_f(cv0);              // lane0 -> 0 via old=0
    const float cdf_lo1 = dpp_up1_f(cv1);
    // cdf_hi = cv unconditionally: at lane63 sw==sw(62) (wc63=0) so cv==cdf_lo
    // when padding==0; and bin-63 output is ts[63] regardless since (ta-tb)=0.
    // ts_hi: lane63 DPP old=0, ts>0 -> fmax restores t (sorted ts makes fmax
    // a no-op for lanes 0..62).
    const float ts_hi0 = fmaxf(dpp_dn1_f(t0), t0);
    const float ts_hi1 = fmaxf(dpp_dn1_f(t1), t1);

    pack0[lane] = make_float4(cdf_lo0, t0, cv0, ts_hi0);
    pack1[lane] = make_float4(cdf_lo1, t1, cv1, ts_hi1);
    ((int2*)A0)[lane] = make_int2(0, 0);               // init slots 0..127
    ((int2*)A1)[lane] = make_int2(0, 0);

    // exact r = #{ j in [0,128): fl(j*C127) < cdf_lo }; est rel-err <= 2^-24
    // -> true r in {base..base+2} (window proven R5).
    int b0 = (int)(cdf_lo0 * 127.0f); b0 = (b0 > 125) ? 125 : b0;
    int b1 = (int)(cdf_lo1 * 127.0f); b1 = (b1 > 125) ? 125 : b1;
    int r0 = b0, r1 = b1;
    #pragma unroll
    for (int d = 0; d < 3; ++d) {
        const int j0 = b0 + d;
        const int j1 = b1 + d;
        if ((float)j0 * C127 < cdf_lo0) r0 = j0 + 1;
        if ((float)j1 * C127 < cdf_lo1) r1 = j1 + 1;
    }

    // Interleaved dedup-scatter: A'[2r] for r<64, A'[2r-127] for r>=64
    // (r=128 -> slot 129: allocated, never read). Injective in r.
    const int mr0 = (r0 < 64) ? (2 * r0) : (2 * r0 - 127);
    const int mr1 = (r1 < 64) ? (2 * r1) : (2 * r1 - 127);
    const int rn0 = dpp_dn1_i(r0);                     // lane63 -> 0 (forced)
    const int rn1 = dpp_dn1_i(r1);
    if ((lane == 63) || (rn0 > r0)) A0[mr0] = lane;    // last k of each r-run
    if ((lane == 63) || (rn1 > r1)) A1[mr1] = lane;

    // merge position of ts[lane] is exactly r (identity proven R6); fire early.
    float* __restrict__ orow0 = out + (size_t)row0 * 192;
    float* __restrict__ orow1 = orow0 + 192;
    orow0[lane + r0] = t0;
    orow1[lane + r1] = t1;

    // one wave-local fence covers all LDS writes of both rows
    asm volatile("s_waitcnt lgkmcnt(0)" ::: "memory");

    // ================= phase 2 (both rows, interleaved) =================
    const int2 av0 = ((const int2*)A0)[lane];
    const int2 av1 = ((const int2*)A1)[lane];
    int i00 = wscan_max_i(av0.x);
    int i10 = wscan_max_i(av1.x);
    const int cA0 = __builtin_amdgcn_readlane(i00, 63);
    const int cA1 = __builtin_amdgcn_readlane(i10, 63);
    int i01 = wscan_max_i(av0.y); i01 = (i01 > cA0) ? i01 : cA0;
    int i11 = wscan_max_i(av1.y); i11 = (i11 > cA1) ? i11 : cA1;

    const float u0 = flane * C127;
    const float u1 = (flane + 64.0f) * C127;
    const float4 p00 = pack0[i00];
    const float4 p01 = pack0[i01];
    const float4 p10 = pack1[i10];
    const float4 p11 = pack1[i11];

    float d00 = p00.z - p00.x; d00 = (d00 < EPSF) ? 1.0f : d00;
    float d01 = p01.z - p01.x; d01 = (d01 < EPSF) ? 1.0f : d01;
    float d10 = p10.z - p10.x; d10 = (d10 < EPSF) ? 1.0f : d10;
    float d11 = p11.z - p11.x; d11 = (d11 < EPSF) ? 1.0f : d11;
    const float nt00 = p00.y + ((u0 - p00.x) * __builtin_amdgcn_rcpf(d00)) * (p00.w - p00.y);
    const float nt01 = p01.y + ((u1 - p01.x) * __builtin_amdgcn_rcpf(d01)) * (p01.w - p01.y);
    const float nt10 = p10.y + ((u0 - p10.x) * __builtin_amdgcn_rcpf(d10)) * (p10.w - p10.y);
    const float nt11 = p11.y + ((u1 - p11.x) * __builtin_amdgcn_rcpf(d11)) * (p11.w - p11.y);

    // merge positions of samples: j + i_j + 1 (t-first tie order);
    // permutation of [0,192) guaranteed combinatorially (monotone r + inverse i).
    orow0[lane + i00 + 1]      = nt00;
    orow0[lane + 64 + i01 + 1] = nt01;
    orow1[lane + i10 + 1]      = nt10;
    orow1[lane + 64 + i11 + 1] = nt11;
}

extern "C" void kernel_launch(void* const* d_in, const int* in_sizes, int n_in,
                              void* d_out, int out_size, void* d_ws, size_t ws_size,
                              hipStream_t stream) {
    const float* weights = (const float*)d_in[0];
    const float* ts      = (const float*)d_in[1];
    float* out           = (float*)d_out;
    const int num_rows = in_sizes[0] / 64;         // 524288 (even)
    const int waves    = (num_rows + 1) / 2;       // 2 rows per wave
    const int blocks   = (waves + 3) / 4;          // 4 waves per block
    pdf_resample_kernel<<<blocks, 256, 0, stream>>>(weights, ts, out, num_rows);
}